// Round 8
// baseline (236.272 us; speedup 1.0000x reference)
//
#include <hip/hip_runtime.h>
#include <cstddef>
#include <cstdint>

#define QLEN   1024
#define SCALE  0.125f
#define LN_EPS 1e-5f
#define DMODEL 1024

typedef __bf16 bf16x8 __attribute__((ext_vector_type(8)));
typedef __bf16 bf16x4 __attribute__((ext_vector_type(4)));
typedef float  f32x4  __attribute__((ext_vector_type(4)));

__device__ __forceinline__ void load16_lds(const void* g, void* l) {
  __builtin_amdgcn_global_load_lds(
      (const __attribute__((address_space(1))) unsigned int*)g,
      (__attribute__((address_space(3))) unsigned int*)l, 16, 0, 0);
}

// LDS-only barrier: drain ds ops, but leave global loads (vmcnt) in flight.
__device__ __forceinline__ void bar_lds() {
  asm volatile("s_waitcnt lgkmcnt(0)" ::: "memory");
  __builtin_amdgcn_s_barrier();
  asm volatile("" ::: "memory");
}

// ---------------------------------------------------------------------------
// One cast kernel for all five fp32->bf16 inputs (block-range partitioned).
// ---------------------------------------------------------------------------
__global__ __launch_bounds__(256) void cast_all(
    const float* __restrict__ w, __bf16* __restrict__ w_bf,
    const float* __restrict__ Wqkv, __bf16* __restrict__ Wqkv_bf,
    const float* __restrict__ r, __bf16* __restrict__ r_bf,
    const float* __restrict__ Wr, __bf16* __restrict__ Wr_bf,
    const float* __restrict__ Wo, __bf16* __restrict__ Wo_bf)
{
  int blk = blockIdx.x;
  const float* in; __bf16* out;
  if (blk < 2048)      { in = w;    out = w_bf;    }
  else if (blk < 2688) { blk -= 2048; in = Wqkv; out = Wqkv_bf; }
  else if (blk < 3200) { blk -= 2688; in = r;    out = r_bf;    }
  else if (blk < 3264) { blk -= 3200; in = Wr;   out = Wr_bf;   }
  else                 { blk -= 3264; in = Wo;   out = Wo_bf;   }
  const size_t i = ((size_t)blk * 256 + threadIdx.x) * 8;
  const float4 a = *(const float4*)&in[i];
  const float4 b = *(const float4*)&in[i + 4];
  bf16x8 o;
  o[0] = (__bf16)a.x; o[1] = (__bf16)a.y; o[2] = (__bf16)a.z; o[3] = (__bf16)a.w;
  o[4] = (__bf16)b.x; o[5] = (__bf16)b.y; o[6] = (__bf16)b.z; o[7] = (__bf16)b.w;
  *(bf16x8*)&out[i] = o;
}

// ---------------------------------------------------------------------------
// Merged projection GEMM, 128x64 tiles, BK=64 (24 KB LDS, 16 K-iterations):
// halves the number of vmcnt(0)+barrier stall windows vs BK=32; staging and
// fragment reads reuse gemm64's verified [row][64] 8-slot XOR pattern.
//  blocks [0,640):  QKV: [4096,1280] = w_bf @ Wqkv_bf^T, scatter epilogue.
//  blocks [640,656): r:  [1024,128] = r_bf @ Wr_bf^T -> Rb[g][i][64].
// ---------------------------------------------------------------------------
__global__ __launch_bounds__(256) void gemm_proj(
    const __bf16* __restrict__ w_bf, const __bf16* __restrict__ Wqkv_bf,
    const __bf16* __restrict__ r_bf, const __bf16* __restrict__ Wr_bf,
    const float* __restrict__ rwb, const float* __restrict__ rrb,
    __bf16* __restrict__ Qw, __bf16* __restrict__ Qr,
    __bf16* __restrict__ Kb, __bf16* __restrict__ Vt,
    __bf16* __restrict__ Rb)
{
  __shared__ __bf16 Asl[128 * 64];
  __shared__ __bf16 Bsl[64 * 64];
  const int blk = blockIdx.x;
  const bool isR = blk >= 640;
  const __bf16 *A, *B;
  int m0, n0;
  if (!isR) { A = w_bf; B = Wqkv_bf; n0 = (blk % 20) * 64; m0 = (blk / 20) * 128; }
  else      { const int k = blk - 640; A = r_bf; B = Wr_bf;
              n0 = (k % 2) * 64; m0 = (k / 2) * 128; }

  const int tid = threadIdx.x, lane = tid & 63, wv = tid >> 6;
  const int lr = lane & 15, kq = lane >> 4;
  const int s = lane & 7, ar = lane >> 3;

  f32x4 acc[2][4];
#pragma unroll
  for (int mt = 0; mt < 2; ++mt)
#pragma unroll
    for (int nt = 0; nt < 4; ++nt)
      acc[mt][nt] = (f32x4){0.f, 0.f, 0.f, 0.f};

  for (int k0 = 0; k0 < 1024; k0 += 64) {
#pragma unroll
    for (int p = 0; p < 4; ++p) {
      const int row = wv * 32 + p * 8 + ar;
      const int gc = (s - (row & 7)) & 7;
      load16_lds(A + (size_t)(m0 + row) * 1024 + k0 + gc * 8,
                 &Asl[row * 64 + s * 8]);
    }
#pragma unroll
    for (int p = 0; p < 2; ++p) {
      const int row = wv * 16 + p * 8 + ar;
      const int gc = (s - (row & 7)) & 7;
      load16_lds(B + (size_t)(n0 + row) * 1024 + k0 + gc * 8,
                 &Bsl[row * 64 + s * 8]);
    }
    __syncthreads();
#pragma unroll
    for (int ks = 0; ks < 2; ++ks) {
      const int c = ks * 4 + kq;
      bf16x8 af[2], bfr[4];
#pragma unroll
      for (int mt = 0; mt < 2; ++mt) {
        const int row = wv * 32 + mt * 16 + lr;
        af[mt] = *(const bf16x8*)&Asl[row * 64 + ((c + (row & 7)) & 7) * 8];
      }
#pragma unroll
      for (int nt = 0; nt < 4; ++nt) {
        const int row = nt * 16 + lr;
        bfr[nt] = *(const bf16x8*)&Bsl[row * 64 + ((c + (row & 7)) & 7) * 8];
      }
#pragma unroll
      for (int mt = 0; mt < 2; ++mt)
#pragma unroll
        for (int nt = 0; nt < 4; ++nt)
          acc[mt][nt] = __builtin_amdgcn_mfma_f32_16x16x32_bf16(
              af[mt], bfr[nt], acc[mt][nt], 0, 0, 0);
    }
    __syncthreads();
  }

#pragma unroll
  for (int mt = 0; mt < 2; ++mt) {
    const int row0 = m0 + wv * 32 + mt * 16 + kq * 4;
#pragma unroll
    for (int nt = 0; nt < 4; ++nt) {
      const int gcol = n0 + nt * 16 + lr;
      const f32x4 c = acc[mt][nt];
      if (isR) {
        const int g = gcol >> 6, d = gcol & 63;
#pragma unroll
        for (int reg = 0; reg < 4; ++reg)
          Rb[(size_t)g * 65536 + (size_t)(row0 + reg) * 64 + d] = (__bf16)c[reg];
      } else if (gcol < 128) {       // Q
        const int g = gcol >> 6, d = gcol & 63;
        const float bw = rwb[gcol], br = rrb[gcol];
#pragma unroll
        for (int reg = 0; reg < 4; ++reg) {
          const int row = row0 + reg, i = row >> 2, b = row & 3;
          const size_t o = (size_t)(b * 2 + g) * 65536 + (size_t)i * 64 + d;
          Qw[o] = (__bf16)(c[reg] + bw);
          Qr[o] = (__bf16)(c[reg] + br);
        }
      } else if (gcol < 256) {       // K
        const int lc = gcol - 128, g = lc >> 6, d = lc & 63;
#pragma unroll
        for (int reg = 0; reg < 4; ++reg) {
          const int row = row0 + reg, i = row >> 2, b = row & 3;
          Kb[(size_t)(b * 2 + g) * 65536 + (size_t)i * 64 + d] = (__bf16)c[reg];
        }
      } else {                       // V -> transposed Vt
        const int lc = gcol - 256, h = lc >> 6, d = lc & 63;
#pragma unroll
        for (int reg = 0; reg < 4; ++reg) {
          const int row = row0 + reg, i = row >> 2, b = row & 3;
          Vt[((size_t)((b * 16 + h) * 64 + d)) * 1024 + i] = (__bf16)c[reg];
        }
      }
    }
  }
}

// ---------------------------------------------------------------------------
// Wo projection, 128x64 tiles, BK=64, K-SPLIT x2 (grid (16,32,2) = 1024
// blocks, 8 K-iterations each). Partials to C0/C1; ln sums them.
// ---------------------------------------------------------------------------
__global__ __launch_bounds__(256) void gemm_wo(
    const __bf16* __restrict__ A, const __bf16* __restrict__ B,
    float* __restrict__ C0, float* __restrict__ C1)
{
  __shared__ __bf16 Asl[128 * 64];
  __shared__ __bf16 Bsl[64 * 64];
  const int m0 = blockIdx.y * 128, n0 = blockIdx.x * 64;
  const int kh = blockIdx.z;
  float* __restrict__ C = kh ? C1 : C0;
  const int tid = threadIdx.x, lane = tid & 63, wv = tid >> 6;
  const int lr = lane & 15, kq = lane >> 4;
  const int s = lane & 7, ar = lane >> 3;
  const int kbase = kh * 512;

  f32x4 acc[2][4];
#pragma unroll
  for (int mt = 0; mt < 2; ++mt)
#pragma unroll
    for (int nt = 0; nt < 4; ++nt)
      acc[mt][nt] = (f32x4){0.f, 0.f, 0.f, 0.f};

  for (int k0 = 0; k0 < 512; k0 += 64) {
#pragma unroll
    for (int p = 0; p < 4; ++p) {
      const int row = wv * 32 + p * 8 + ar;
      const int gc = (s - (row & 7)) & 7;
      load16_lds(A + (size_t)(m0 + row) * 1024 + kbase + k0 + gc * 8,
                 &Asl[row * 64 + s * 8]);
    }
#pragma unroll
    for (int p = 0; p < 2; ++p) {
      const int row = wv * 16 + p * 8 + ar;
      const int gc = (s - (row & 7)) & 7;
      load16_lds(B + (size_t)(n0 + row) * 1024 + kbase + k0 + gc * 8,
                 &Bsl[row * 64 + s * 8]);
    }
    __syncthreads();
#pragma unroll
    for (int ks = 0; ks < 2; ++ks) {
      const int c = ks * 4 + kq;
      bf16x8 af[2], bfr[4];
#pragma unroll
      for (int mt = 0; mt < 2; ++mt) {
        const int row = wv * 32 + mt * 16 + lr;
        af[mt] = *(const bf16x8*)&Asl[row * 64 + ((c + (row & 7)) & 7) * 8];
      }
#pragma unroll
      for (int nt = 0; nt < 4; ++nt) {
        const int row = nt * 16 + lr;
        bfr[nt] = *(const bf16x8*)&Bsl[row * 64 + ((c + (row & 7)) & 7) * 8];
      }
#pragma unroll
      for (int mt = 0; mt < 2; ++mt)
#pragma unroll
        for (int nt = 0; nt < 4; ++nt)
          acc[mt][nt] = __builtin_amdgcn_mfma_f32_16x16x32_bf16(
              af[mt], bfr[nt], acc[mt][nt], 0, 0, 0);
    }
    __syncthreads();
  }

#pragma unroll
  for (int mt = 0; mt < 2; ++mt) {
    const int row0 = m0 + wv * 32 + mt * 16 + kq * 4;
#pragma unroll
    for (int nt = 0; nt < 4; ++nt) {
      const int col = n0 + nt * 16 + lr;
      const f32x4 c = acc[mt][nt];
#pragma unroll
      for (int reg = 0; reg < 4; ++reg)
        C[(size_t)(row0 + reg) * 1024 + col] = c[reg];
    }
  }
}

// ---------------------------------------------------------------------------
// Batched K=64 bf16 MFMA GEMM for AC/BD. BD epilogue writes the rel-SHIFTED
// layout directly: raw[k][c] -> out[k][c-(1023-k)] if c>=1023-k,
// else out[k-1][c+k+1]; thread at c==1023-k also zeroes out[k][k+1].
// Coverage per out row i: (i+1) + 1 + (1022-i) = 1024.
// ---------------------------------------------------------------------------
__global__ __launch_bounds__(256) void gemm64_bf16(
    const __bf16* __restrict__ Qw, const __bf16* __restrict__ Qr,
    const __bf16* __restrict__ Kb, const __bf16* __restrict__ Rb,
    __bf16* __restrict__ AC, __bf16* __restrict__ BDo)
{
  __shared__ __bf16 Asl[128 * 64];
  __shared__ __bf16 Bsl[128 * 64];
  const int tid = threadIdx.x, lane = tid & 63, wv = tid >> 6;
  const int which = blockIdx.z & 1, bat = blockIdx.z >> 1;
  const int m0 = blockIdx.y * 128, n0 = blockIdx.x * 128;
  const __bf16* Ap = (which ? Qr : Qw) + (size_t)bat * 65536;
  const __bf16* Bp = which ? (Rb + (size_t)(bat & 1) * 65536)
                           : (Kb + (size_t)bat * 65536);
  __bf16* Cp = (which ? BDo : AC) + (size_t)bat * 1048576;

#pragma unroll
  for (int p = 0; p < 4; ++p) {
    const int row = wv * 32 + p * 8 + (lane >> 3);
    const int s = lane & 7;
    const int gc = (s - (row & 7)) & 7;
    load16_lds(Ap + (size_t)(m0 + row) * 64 + gc * 8, &Asl[row * 64 + s * 8]);
    load16_lds(Bp + (size_t)(n0 + row) * 64 + gc * 8, &Bsl[row * 64 + s * 8]);
  }
  __syncthreads();

  const int lr = lane & 15, kq = lane >> 4;
  const int wm = (wv >> 1) * 64, wn = (wv & 1) * 64;
  f32x4 acc[4][4];
#pragma unroll
  for (int mt = 0; mt < 4; ++mt)
#pragma unroll
    for (int nt = 0; nt < 4; ++nt)
      acc[mt][nt] = (f32x4){0.f, 0.f, 0.f, 0.f};

#pragma unroll
  for (int ks = 0; ks < 2; ++ks) {
    const int c = ks * 4 + kq;
    bf16x8 af[4], bfr[4];
#pragma unroll
    for (int mt = 0; mt < 4; ++mt) {
      const int row = wm + mt * 16 + lr;
      af[mt] = *(const bf16x8*)&Asl[row * 64 + ((c + (row & 7)) & 7) * 8];
    }
#pragma unroll
    for (int nt = 0; nt < 4; ++nt) {
      const int row = wn + nt * 16 + lr;
      bfr[nt] = *(const bf16x8*)&Bsl[row * 64 + ((c + (row & 7)) & 7) * 8];
    }
#pragma unroll
    for (int mt = 0; mt < 4; ++mt)
#pragma unroll
      for (int nt = 0; nt < 4; ++nt)
        acc[mt][nt] = __builtin_amdgcn_mfma_f32_16x16x32_bf16(
            af[mt], bfr[nt], acc[mt][nt], 0, 0, 0);
  }

#pragma unroll
  for (int mt = 0; mt < 4; ++mt) {
    const int row0 = m0 + wm + mt * 16 + kq * 4;
#pragma unroll
    for (int nt = 0; nt < 4; ++nt) {
      const int col = n0 + wn + nt * 16 + lr;
      const f32x4 cc = acc[mt][nt];
      if (which) {
        // shifted-BD scatter
#pragma unroll
        for (int reg = 0; reg < 4; ++reg) {
          const int k = row0 + reg;
          const int thr = 1023 - k;
          if (col >= thr) {
            Cp[(size_t)k * 1024 + (col - thr)] = (__bf16)cc[reg];
            if (col == thr && k < 1023)
              Cp[(size_t)k * 1024 + (k + 1)] = (__bf16)0.f;
          } else if (k > 0) {
            Cp[(size_t)(k - 1) * 1024 + (col + k + 1)] = (__bf16)cc[reg];
          }
        }
      } else {
#pragma unroll
        for (int reg = 0; reg < 4; ++reg)
          Cp[(size_t)(row0 + reg) * 1024 + col] = (__bf16)cc[reg];
      }
    }
  }
}

// ---------------------------------------------------------------------------
// prep3: blocks [0,2048) = vectorized T = (AC + BDs)*SCALE (all three same
// layout, bf16x8 streams); blocks [2048,3072) = per-head mixed masks Mh.
// ---------------------------------------------------------------------------
__global__ __launch_bounds__(256) void prep3(
    const __bf16* __restrict__ AC, const __bf16* __restrict__ BDs,
    __bf16* __restrict__ Tg,
    const float* __restrict__ masks, const float* __restrict__ mproj,
    __bf16* __restrict__ Mh)
{
  const int tid = threadIdx.x;
  if (blockIdx.x < 2048) {
    const size_t base = (size_t)blockIdx.x * 4096 + (size_t)tid * 16;
    const bf16x8 a0 = *(const bf16x8*)&AC[base];
    const bf16x8 a1 = *(const bf16x8*)&AC[base + 8];
    const bf16x8 b0 = *(const bf16x8*)&BDs[base];
    const bf16x8 b1 = *(const bf16x8*)&BDs[base + 8];
    bf16x8 o0, o1;
#pragma unroll
    for (int k = 0; k < 8; ++k) {
      o0[k] = (__bf16)(((float)a0[k] + (float)b0[k]) * SCALE);
      o1[k] = (__bf16)(((float)a1[k] + (float)b1[k]) * SCALE);
    }
    *(bf16x8*)&Tg[base] = o0;
    *(bf16x8*)&Tg[base + 8] = o1;
  } else {
    const int blk = blockIdx.x - 2048;
    const size_t ij0 = ((size_t)blk * 256 + tid) * 4;
    const float4 a = *(const float4*)&masks[ij0 * 3];
    const float4 b = *(const float4*)&masks[ij0 * 3 + 4];
    const float4 c = *(const float4*)&masks[ij0 * 3 + 8];
    const float m0[4] = {a.x, a.w, b.z, c.y};
    const float m1[4] = {a.y, b.x, b.w, c.z};
    const float m2[4] = {a.z, b.y, c.x, c.w};
#pragma unroll
    for (int h = 0; h < 16; ++h) {
      const float p0 = mproj[h], p1 = mproj[16 + h], p2 = mproj[32 + h];
      bf16x4 o;
#pragma unroll
      for (int k = 0; k < 4; ++k)
        o[k] = (__bf16)(m0[k] * p0 + m1[k] * p1 + m2[k] * p2);
      *(bf16x4*)&Mh[(size_t)h * 1048576 + ij0] = o;
    }
  }
}

// ---------------------------------------------------------------------------
// attn10: chunk=128, 6 blocks/CU, pipelined + setprio on MFMA (r7 best).
// grid (32, 16, 4).
// ---------------------------------------------------------------------------
__global__ __launch_bounds__(256, 6) void attn10(
    const __bf16* __restrict__ Tg, const __bf16* __restrict__ Mh,
    const __bf16* __restrict__ Vt, __bf16* __restrict__ av)
{
  __shared__ __bf16 P[2][32 * 128];
  __shared__ float rinvS[32];
  const int tid = threadIdx.x;
  const int i0 = blockIdx.x * 32;
  const int h = blockIdx.y, b = blockIdx.z;
  const int g = h >> 3;
  const size_t bg = (size_t)(b * 2 + g);
  const int r = tid >> 3, li = tid & 7;
  const __bf16* Trow = Tg + bg * 1048576 + (size_t)(i0 + r) * 1024 + li * 8;
  const __bf16* Mrow = Mh + (size_t)h * 1048576 + (size_t)(i0 + r) * 1024 + li * 8;

  const int lane = tid & 63, wv = tid >> 6;
  const int m = lane & 15, kq = lane >> 4;
  const __bf16* vbase = Vt + ((size_t)((b * 16 + h) * 64 + wv * 16 + m)) * 1024 + kq * 8;

  float sum = 0.f;
  f32x4 acc[2][2];
#pragma unroll
  for (int mt = 0; mt < 2; ++mt)
#pragma unroll
    for (int u = 0; u < 2; ++u)
      acc[mt][u] = (f32x4){0.f, 0.f, 0.f, 0.f};

  bf16x8 t[2], mk[2], v[4];
#pragma unroll
  for (int q = 0; q < 2; ++q) {
    t[q]  = *(const bf16x8*)&Trow[q * 64];
    mk[q] = *(const bf16x8*)&Mrow[q * 64];
  }

  for (int ch = 0; ch < 8; ++ch) {
    const int cb = ch & 1;
#pragma unroll
    for (int ks = 0; ks < 4; ++ks)
      v[ks] = *(const bf16x8*)&vbase[(ch * 4 + ks) * 32];
#pragma unroll
    for (int q = 0; q < 2; ++q) {
      bf16x8 p8;
      float s0 = 0.f;
#pragma unroll
      for (int k = 0; k < 8; ++k) {
        const float e = __expf((float)t[q][k] * (float)mk[q][k]);
        s0 += e;
        p8[k] = (__bf16)e;
      }
      sum += s0;
      const int slot = (q * 8 + li) ^ (r & 7);
      *(bf16x8*)&P[cb][r * 128 + slot * 8] = p8;
    }
    if (ch < 7) {
#pragma unroll
      for (int q = 0; q < 2; ++q) {
        t[q]  = *(const bf16x8*)&Trow[(ch + 1) * 128 + q * 64];
        mk[q] = *(const bf16x8*)&Mrow[(ch + 1) * 128 + q * 64];
      }
    }
    bar_lds();
    __builtin_amdgcn_s_setprio(1);
#pragma unroll
    for (int ks = 0; ks < 4; ++ks) {
      const int c = ks * 4 + kq;
#pragma unroll
      for (int mt = 0; mt < 2; ++mt) {
        const int R = mt * 16 + m;
        const bf16x8 a = *(const bf16x8*)&P[cb][R * 128 + ((c ^ (R & 7)) << 3)];
        acc[mt][ks & 1] = __builtin_amdgcn_mfma_f32_16x16x32_bf16(
            a, v[ks], acc[mt][ks & 1], 0, 0, 0);
      }
    }
    __builtin_amdgcn_s_setprio(0);
  }

  sum += __shfl_xor(sum, 1);
  sum += __shfl_xor(sum, 2);
  sum += __shfl_xor(sum, 4);
  if (li == 0) rinvS[r] = 1.f / sum;
  __syncthreads();

#pragma unroll
  for (int mt = 0; mt < 2; ++mt) {
    const f32x4 accf = acc[mt][0] + acc[mt][1];
#pragma unroll
    for (int reg = 0; reg < 4; ++reg) {
      const int row = mt * 16 + kq * 4 + reg;
      av[((size_t)(i0 + row) * 4 + b) * 1024 + h * 64 + wv * 16 + m] =
          (__bf16)(accf[reg] * rinvS[row]);
    }
  }
}

// ---------------------------------------------------------------------------
// residual + LayerNorm: float4 loads, wave-shuffle reduce (2 barriers).
// Sums the two K-split partials of the Wo projection.
// ---------------------------------------------------------------------------
__global__ __launch_bounds__(256) void ln_kernel(
    const float* __restrict__ w, const float* __restrict__ ao0,
    const float* __restrict__ ao1,
    const float* __restrict__ gamma, const float* __restrict__ beta,
    float* __restrict__ out)
{
  const int tid = threadIdx.x;
  const int lane = tid & 63, wv = tid >> 6;
  const size_t base = (size_t)blockIdx.x * DMODEL + tid * 4;
  __shared__ float red[8];
  const float4 xw = *(const float4*)&w[base];
  const float4 xa = *(const float4*)&ao0[base];
  const float4 xb = *(const float4*)&ao1[base];
  float x[4] = {xw.x + xa.x + xb.x, xw.y + xa.y + xb.y,
                xw.z + xa.z + xb.z, xw.w + xa.w + xb.w};
  float s = (x[0] + x[1]) + (x[2] + x[3]);
  s += __shfl_xor(s, 1);  s += __shfl_xor(s, 2);  s += __shfl_xor(s, 4);
  s += __shfl_xor(s, 8);  s += __shfl_xor(s, 16); s += __shfl_xor(s, 32);
  if (lane == 0) red[wv] = s;
  __syncthreads();
  const float mu = (red[0] + red[1] + red[2] + red[3]) * (1.f / DMODEL);
  float s2 = 0.f;
#pragma unroll
  for (int p = 0; p < 4; ++p) { const float t = x[p] - mu; s2 += t * t; }
  s2 += __shfl_xor(s2, 1);  s2 += __shfl_xor(s2, 2);  s2 += __shfl_xor(s2, 4);
  s2 += __shfl_xor(s2, 8);  s2 += __shfl_xor(s2, 16); s2 += __shfl_xor(s2, 32);
  if (lane == 0) red[4 + wv] = s2;
  __syncthreads();
  const float rs = rsqrtf((red[4] + red[5] + red[6] + red[7]) * (1.f / DMODEL) + LN_EPS);
  const float4 g4 = *(const float4*)&gamma[tid * 4];
  const float4 b4 = *(const float4*)&beta[tid * 4];
  float4 o;
  o.x = (x[0] - mu) * rs * g4.x + b4.x;
  o.y = (x[1] - mu) * rs * g4.y + b4.y;
  o.z = (x[2] - mu) * rs * g4.z + b4.z;
  o.w = (x[3] - mu) * rs * g4.w + b4.w;
  *(float4*)&out[base] = o;
}

// ---------------------------------------------------------------------------
extern "C" void kernel_launch(void* const* d_in, const int* in_sizes, int n_in,
                              void* d_out, int out_size, void* d_ws, size_t ws_size,
                              hipStream_t stream)
{
  const float* w     = (const float*)d_in[0];
  const float* r     = (const float*)d_in[1];
  const float* rwb   = (const float*)d_in[2];
  const float* rrb   = (const float*)d_in[3];
  const float* masks = (const float*)d_in[4];
  const float* Wqkv  = (const float*)d_in[5];
  const float* Wr    = (const float*)d_in[6];
  const float* mproj = (const float*)d_in[7];
  const float* Wo    = (const float*)d_in[8];
  const float* gam   = (const float*)d_in[9];
  const float* bet   = (const float*)d_in[10];
  float* out = (float*)d_out;

  float* ws = (float*)d_ws;
  // fp32-unit offsets; total 25,690,112 f = 102.8 MB
  __bf16* w_bf    = (__bf16*)(ws);                   // 2,097,152 f
  __bf16* Wqkv_bf = (__bf16*)(ws + 2097152);         //   655,360 f
  __bf16* r_bf    = (__bf16*)(ws + 2752512);         //   524,288 f
  __bf16* Wr_bf   = (__bf16*)(ws + 3276800);         //    65,536 f
  __bf16* Qw      = (__bf16*)(ws + 3342336);         //   262,144 f
  __bf16* Qr      = (__bf16*)(ws + 3604480);
  __bf16* Kb      = (__bf16*)(ws + 3866624);
  __bf16* Rb      = (__bf16*)(ws + 4128768);         //    65,536 f
  __bf16* Mh      = (__bf16*)(ws);                   // 8,388,608 f (post-gemm_proj)
  __bf16* AC_bf   = (__bf16*)(ws + 8388608);         // 4,194,304 f
  float*  ao0     = ws + 8388608;                    // overlays AC (post-prep3)
  __bf16* BD_bf   = (__bf16*)(ws + 12582912);        // 4,194,304 f (SHIFTED)
  float*  ao1     = ws + 12582912;                   // overlays BD (post-prep3)
  __bf16* Tg      = (__bf16*)(ws + 16777216);        // 4,194,304 f
  __bf16* Vt      = (__bf16*)(ws + 20971520);        // 2,097,152 f
  __bf16* av_bf   = (__bf16*)(ws + 23068672);        // 2,097,152 f
  __bf16* Wo_bf   = (__bf16*)(ws + 25165824);        //   524,288 f

  // 1) all input casts
  cast_all<<<3776, 256, 0, stream>>>(w, w_bf, Wqkv, Wqkv_bf, r, r_bf,
                                     Wr, Wr_bf, Wo, Wo_bf);
  // 2) merged QKV + r projections (BK=64, half the barrier windows)
  gemm_proj<<<656, 256, 0, stream>>>(
      w_bf, Wqkv_bf, r_bf, Wr_bf, rwb, rrb, Qw, Qr, Kb, Vt, Rb);
  // 3) AC + shifted-BD via MFMA
  gemm64_bf16<<<dim3(8, 8, 16), 256, 0, stream>>>(Qw, Qr, Kb, Rb, AC_bf, BD_bf);
  // 4) T = (AC+BDs)*SCALE (vectorized) + per-head masks, one dispatch
  prep3<<<3072, 256, 0, stream>>>(AC_bf, BD_bf, Tg, masks, mproj, Mh);
  // 5) attention: chunk=128, 6 blocks/CU, pipelined, setprio on MFMA
  attn10<<<dim3(32, 16, 4), 256, 0, stream>>>(Tg, Mh, Vt, av_bf);
  // 6) output projection, BK=64 K-split x2 -> fp32 partials
  gemm_wo<<<dim3(16, 32, 2), 256, 0, stream>>>(av_bf, Wo_bf, ao0, ao1);
  // 7) residual + LayerNorm (sums the two partials)
  ln_kernel<<<4096, 256, 0, stream>>>(w, ao0, ao1, gam, bet, out);
}

// Round 9
// 230.112 us; speedup vs baseline: 1.0268x; 1.0268x over previous
//
#include <hip/hip_runtime.h>
#include <cstddef>
#include <cstdint>

#define QLEN   1024
#define SCALE  0.125f
#define LN_EPS 1e-5f
#define DMODEL 1024

typedef __bf16 bf16x8 __attribute__((ext_vector_type(8)));
typedef __bf16 bf16x4 __attribute__((ext_vector_type(4)));
typedef float  f32x4  __attribute__((ext_vector_type(4)));

__device__ __forceinline__ void load16_lds(const void* g, void* l) {
  __builtin_amdgcn_global_load_lds(
      (const __attribute__((address_space(1))) unsigned int*)g,
      (__attribute__((address_space(3))) unsigned int*)l, 16, 0, 0);
}

// LDS-only barrier: drain ds ops, but leave global loads (vmcnt) in flight.
__device__ __forceinline__ void bar_lds() {
  asm volatile("s_waitcnt lgkmcnt(0)" ::: "memory");
  __builtin_amdgcn_s_barrier();
  asm volatile("" ::: "memory");
}

// ---------------------------------------------------------------------------
// One cast kernel for all five fp32->bf16 inputs (block-range partitioned).
// ---------------------------------------------------------------------------
__global__ __launch_bounds__(256) void cast_all(
    const float* __restrict__ w, __bf16* __restrict__ w_bf,
    const float* __restrict__ Wqkv, __bf16* __restrict__ Wqkv_bf,
    const float* __restrict__ r, __bf16* __restrict__ r_bf,
    const float* __restrict__ Wr, __bf16* __restrict__ Wr_bf,
    const float* __restrict__ Wo, __bf16* __restrict__ Wo_bf)
{
  int blk = blockIdx.x;
  const float* in; __bf16* out;
  if (blk < 2048)      { in = w;    out = w_bf;    }
  else if (blk < 2688) { blk -= 2048; in = Wqkv; out = Wqkv_bf; }
  else if (blk < 3200) { blk -= 2688; in = r;    out = r_bf;    }
  else if (blk < 3264) { blk -= 3200; in = Wr;   out = Wr_bf;   }
  else                 { blk -= 3264; in = Wo;   out = Wo_bf;   }
  const size_t i = ((size_t)blk * 256 + threadIdx.x) * 8;
  const float4 a = *(const float4*)&in[i];
  const float4 b = *(const float4*)&in[i + 4];
  bf16x8 o;
  o[0] = (__bf16)a.x; o[1] = (__bf16)a.y; o[2] = (__bf16)a.z; o[3] = (__bf16)a.w;
  o[4] = (__bf16)b.x; o[5] = (__bf16)b.y; o[6] = (__bf16)b.z; o[7] = (__bf16)b.w;
  *(bf16x8*)&out[i] = o;
}

// ---------------------------------------------------------------------------
// Merged projection GEMM, 128x64 tiles, BK=64 (24 KB LDS, 16 K-iterations).
//  blocks [0,640):  QKV: [4096,1280] = w_bf @ Wqkv_bf^T, scatter epilogue.
//  blocks [640,656): r:  [1024,128] = r_bf @ Wr_bf^T -> Rb[g][i][64].
// ---------------------------------------------------------------------------
__global__ __launch_bounds__(256) void gemm_proj(
    const __bf16* __restrict__ w_bf, const __bf16* __restrict__ Wqkv_bf,
    const __bf16* __restrict__ r_bf, const __bf16* __restrict__ Wr_bf,
    const float* __restrict__ rwb, const float* __restrict__ rrb,
    __bf16* __restrict__ Qw, __bf16* __restrict__ Qr,
    __bf16* __restrict__ Kb, __bf16* __restrict__ Vt,
    __bf16* __restrict__ Rb)
{
  __shared__ __bf16 Asl[128 * 64];
  __shared__ __bf16 Bsl[64 * 64];
  const int blk = blockIdx.x;
  const bool isR = blk >= 640;
  const __bf16 *A, *B;
  int m0, n0;
  if (!isR) { A = w_bf; B = Wqkv_bf; n0 = (blk % 20) * 64; m0 = (blk / 20) * 128; }
  else      { const int k = blk - 640; A = r_bf; B = Wr_bf;
              n0 = (k % 2) * 64; m0 = (k / 2) * 128; }

  const int tid = threadIdx.x, lane = tid & 63, wv = tid >> 6;
  const int lr = lane & 15, kq = lane >> 4;
  const int s = lane & 7, ar = lane >> 3;

  f32x4 acc[2][4];
#pragma unroll
  for (int mt = 0; mt < 2; ++mt)
#pragma unroll
    for (int nt = 0; nt < 4; ++nt)
      acc[mt][nt] = (f32x4){0.f, 0.f, 0.f, 0.f};

  for (int k0 = 0; k0 < 1024; k0 += 64) {
#pragma unroll
    for (int p = 0; p < 4; ++p) {
      const int row = wv * 32 + p * 8 + ar;
      const int gc = (s - (row & 7)) & 7;
      load16_lds(A + (size_t)(m0 + row) * 1024 + k0 + gc * 8,
                 &Asl[row * 64 + s * 8]);
    }
#pragma unroll
    for (int p = 0; p < 2; ++p) {
      const int row = wv * 16 + p * 8 + ar;
      const int gc = (s - (row & 7)) & 7;
      load16_lds(B + (size_t)(n0 + row) * 1024 + k0 + gc * 8,
                 &Bsl[row * 64 + s * 8]);
    }
    __syncthreads();
#pragma unroll
    for (int ks = 0; ks < 2; ++ks) {
      const int c = ks * 4 + kq;
      bf16x8 af[2], bfr[4];
#pragma unroll
      for (int mt = 0; mt < 2; ++mt) {
        const int row = wv * 32 + mt * 16 + lr;
        af[mt] = *(const bf16x8*)&Asl[row * 64 + ((c + (row & 7)) & 7) * 8];
      }
#pragma unroll
      for (int nt = 0; nt < 4; ++nt) {
        const int row = nt * 16 + lr;
        bfr[nt] = *(const bf16x8*)&Bsl[row * 64 + ((c + (row & 7)) & 7) * 8];
      }
#pragma unroll
      for (int mt = 0; mt < 2; ++mt)
#pragma unroll
        for (int nt = 0; nt < 4; ++nt)
          acc[mt][nt] = __builtin_amdgcn_mfma_f32_16x16x32_bf16(
              af[mt], bfr[nt], acc[mt][nt], 0, 0, 0);
    }
    __syncthreads();
  }

#pragma unroll
  for (int mt = 0; mt < 2; ++mt) {
    const int row0 = m0 + wv * 32 + mt * 16 + kq * 4;
#pragma unroll
    for (int nt = 0; nt < 4; ++nt) {
      const int gcol = n0 + nt * 16 + lr;
      const f32x4 c = acc[mt][nt];
      if (isR) {
        const int g = gcol >> 6, d = gcol & 63;
#pragma unroll
        for (int reg = 0; reg < 4; ++reg)
          Rb[(size_t)g * 65536 + (size_t)(row0 + reg) * 64 + d] = (__bf16)c[reg];
      } else if (gcol < 128) {       // Q
        const int g = gcol >> 6, d = gcol & 63;
        const float bw = rwb[gcol], br = rrb[gcol];
#pragma unroll
        for (int reg = 0; reg < 4; ++reg) {
          const int row = row0 + reg, i = row >> 2, b = row & 3;
          const size_t o = (size_t)(b * 2 + g) * 65536 + (size_t)i * 64 + d;
          Qw[o] = (__bf16)(c[reg] + bw);
          Qr[o] = (__bf16)(c[reg] + br);
        }
      } else if (gcol < 256) {       // K
        const int lc = gcol - 128, g = lc >> 6, d = lc & 63;
#pragma unroll
        for (int reg = 0; reg < 4; ++reg) {
          const int row = row0 + reg, i = row >> 2, b = row & 3;
          Kb[(size_t)(b * 2 + g) * 65536 + (size_t)i * 64 + d] = (__bf16)c[reg];
        }
      } else {                       // V -> transposed Vt
        const int lc = gcol - 256, h = lc >> 6, d = lc & 63;
#pragma unroll
        for (int reg = 0; reg < 4; ++reg) {
          const int row = row0 + reg, i = row >> 2, b = row & 3;
          Vt[((size_t)((b * 16 + h) * 64 + d)) * 1024 + i] = (__bf16)c[reg];
        }
      }
    }
  }
}

// ---------------------------------------------------------------------------
// Wo projection, 128x64 tiles, BK=64, K-SPLIT x2 (grid (16,32,2) = 1024
// blocks, 8 K-iterations each). Partials to C0/C1; ln sums them.
// ---------------------------------------------------------------------------
__global__ __launch_bounds__(256) void gemm_wo(
    const __bf16* __restrict__ A, const __bf16* __restrict__ B,
    float* __restrict__ C0, float* __restrict__ C1)
{
  __shared__ __bf16 Asl[128 * 64];
  __shared__ __bf16 Bsl[64 * 64];
  const int m0 = blockIdx.y * 128, n0 = blockIdx.x * 64;
  const int kh = blockIdx.z;
  float* __restrict__ C = kh ? C1 : C0;
  const int tid = threadIdx.x, lane = tid & 63, wv = tid >> 6;
  const int lr = lane & 15, kq = lane >> 4;
  const int s = lane & 7, ar = lane >> 3;
  const int kbase = kh * 512;

  f32x4 acc[2][4];
#pragma unroll
  for (int mt = 0; mt < 2; ++mt)
#pragma unroll
    for (int nt = 0; nt < 4; ++nt)
      acc[mt][nt] = (f32x4){0.f, 0.f, 0.f, 0.f};

  for (int k0 = 0; k0 < 512; k0 += 64) {
#pragma unroll
    for (int p = 0; p < 4; ++p) {
      const int row = wv * 32 + p * 8 + ar;
      const int gc = (s - (row & 7)) & 7;
      load16_lds(A + (size_t)(m0 + row) * 1024 + kbase + k0 + gc * 8,
                 &Asl[row * 64 + s * 8]);
    }
#pragma unroll
    for (int p = 0; p < 2; ++p) {
      const int row = wv * 16 + p * 8 + ar;
      const int gc = (s - (row & 7)) & 7;
      load16_lds(B + (size_t)(n0 + row) * 1024 + kbase + k0 + gc * 8,
                 &Bsl[row * 64 + s * 8]);
    }
    __syncthreads();
#pragma unroll
    for (int ks = 0; ks < 2; ++ks) {
      const int c = ks * 4 + kq;
      bf16x8 af[2], bfr[4];
#pragma unroll
      for (int mt = 0; mt < 2; ++mt) {
        const int row = wv * 32 + mt * 16 + lr;
        af[mt] = *(const bf16x8*)&Asl[row * 64 + ((c + (row & 7)) & 7) * 8];
      }
#pragma unroll
      for (int nt = 0; nt < 4; ++nt) {
        const int row = nt * 16 + lr;
        bfr[nt] = *(const bf16x8*)&Bsl[row * 64 + ((c + (row & 7)) & 7) * 8];
      }
#pragma unroll
      for (int mt = 0; mt < 2; ++mt)
#pragma unroll
        for (int nt = 0; nt < 4; ++nt)
          acc[mt][nt] = __builtin_amdgcn_mfma_f32_16x16x32_bf16(
              af[mt], bfr[nt], acc[mt][nt], 0, 0, 0);
    }
    __syncthreads();
  }

#pragma unroll
  for (int mt = 0; mt < 2; ++mt) {
    const int row0 = m0 + wv * 32 + mt * 16 + kq * 4;
#pragma unroll
    for (int nt = 0; nt < 4; ++nt) {
      const int col = n0 + nt * 16 + lr;
      const f32x4 c = acc[mt][nt];
#pragma unroll
      for (int reg = 0; reg < 4; ++reg)
        C[(size_t)(row0 + reg) * 1024 + col] = c[reg];
    }
  }
}

// ---------------------------------------------------------------------------
// Batched K=64 bf16 MFMA GEMM for AC/BD. BD epilogue writes the rel-SHIFTED
// layout directly: raw[k][c] -> out[k][c-(1023-k)] if c>=1023-k,
// else out[k-1][c+k+1]; thread at c==1023-k also zeroes out[k][k+1].
// ---------------------------------------------------------------------------
__global__ __launch_bounds__(256) void gemm64_bf16(
    const __bf16* __restrict__ Qw, const __bf16* __restrict__ Qr,
    const __bf16* __restrict__ Kb, const __bf16* __restrict__ Rb,
    __bf16* __restrict__ AC, __bf16* __restrict__ BDo)
{
  __shared__ __bf16 Asl[128 * 64];
  __shared__ __bf16 Bsl[128 * 64];
  const int tid = threadIdx.x, lane = tid & 63, wv = tid >> 6;
  const int which = blockIdx.z & 1, bat = blockIdx.z >> 1;
  const int m0 = blockIdx.y * 128, n0 = blockIdx.x * 128;
  const __bf16* Ap = (which ? Qr : Qw) + (size_t)bat * 65536;
  const __bf16* Bp = which ? (Rb + (size_t)(bat & 1) * 65536)
                           : (Kb + (size_t)bat * 65536);
  __bf16* Cp = (which ? BDo : AC) + (size_t)bat * 1048576;

#pragma unroll
  for (int p = 0; p < 4; ++p) {
    const int row = wv * 32 + p * 8 + (lane >> 3);
    const int s = lane & 7;
    const int gc = (s - (row & 7)) & 7;
    load16_lds(Ap + (size_t)(m0 + row) * 64 + gc * 8, &Asl[row * 64 + s * 8]);
    load16_lds(Bp + (size_t)(n0 + row) * 64 + gc * 8, &Bsl[row * 64 + s * 8]);
  }
  __syncthreads();

  const int lr = lane & 15, kq = lane >> 4;
  const int wm = (wv >> 1) * 64, wn = (wv & 1) * 64;
  f32x4 acc[4][4];
#pragma unroll
  for (int mt = 0; mt < 4; ++mt)
#pragma unroll
    for (int nt = 0; nt < 4; ++nt)
      acc[mt][nt] = (f32x4){0.f, 0.f, 0.f, 0.f};

#pragma unroll
  for (int ks = 0; ks < 2; ++ks) {
    const int c = ks * 4 + kq;
    bf16x8 af[4], bfr[4];
#pragma unroll
    for (int mt = 0; mt < 4; ++mt) {
      const int row = wm + mt * 16 + lr;
      af[mt] = *(const bf16x8*)&Asl[row * 64 + ((c + (row & 7)) & 7) * 8];
    }
#pragma unroll
    for (int nt = 0; nt < 4; ++nt) {
      const int row = wn + nt * 16 + lr;
      bfr[nt] = *(const bf16x8*)&Bsl[row * 64 + ((c + (row & 7)) & 7) * 8];
    }
#pragma unroll
    for (int mt = 0; mt < 4; ++mt)
#pragma unroll
      for (int nt = 0; nt < 4; ++nt)
        acc[mt][nt] = __builtin_amdgcn_mfma_f32_16x16x32_bf16(
            af[mt], bfr[nt], acc[mt][nt], 0, 0, 0);
  }

#pragma unroll
  for (int mt = 0; mt < 4; ++mt) {
    const int row0 = m0 + wm + mt * 16 + kq * 4;
#pragma unroll
    for (int nt = 0; nt < 4; ++nt) {
      const int col = n0 + wn + nt * 16 + lr;
      const f32x4 cc = acc[mt][nt];
      if (which) {
        // shifted-BD scatter
#pragma unroll
        for (int reg = 0; reg < 4; ++reg) {
          const int k = row0 + reg;
          const int thr = 1023 - k;
          if (col >= thr) {
            Cp[(size_t)k * 1024 + (col - thr)] = (__bf16)cc[reg];
            if (col == thr && k < 1023)
              Cp[(size_t)k * 1024 + (k + 1)] = (__bf16)0.f;
          } else if (k > 0) {
            Cp[(size_t)(k - 1) * 1024 + (col + k + 1)] = (__bf16)cc[reg];
          }
        }
      } else {
#pragma unroll
        for (int reg = 0; reg < 4; ++reg)
          Cp[(size_t)(row0 + reg) * 1024 + col] = (__bf16)cc[reg];
      }
    }
  }
}

// ---------------------------------------------------------------------------
// prep3: blocks [0,2048) = vectorized T = (AC + BDs)*SCALE (all three same
// layout, bf16x8 streams); blocks [2048,3072) = per-head mixed masks Mh.
// ---------------------------------------------------------------------------
__global__ __launch_bounds__(256) void prep3(
    const __bf16* __restrict__ AC, const __bf16* __restrict__ BDs,
    __bf16* __restrict__ Tg,
    const float* __restrict__ masks, const float* __restrict__ mproj,
    __bf16* __restrict__ Mh)
{
  const int tid = threadIdx.x;
  if (blockIdx.x < 2048) {
    const size_t base = (size_t)blockIdx.x * 4096 + (size_t)tid * 16;
    const bf16x8 a0 = *(const bf16x8*)&AC[base];
    const bf16x8 a1 = *(const bf16x8*)&AC[base + 8];
    const bf16x8 b0 = *(const bf16x8*)&BDs[base];
    const bf16x8 b1 = *(const bf16x8*)&BDs[base + 8];
    bf16x8 o0, o1;
#pragma unroll
    for (int k = 0; k < 8; ++k) {
      o0[k] = (__bf16)(((float)a0[k] + (float)b0[k]) * SCALE);
      o1[k] = (__bf16)(((float)a1[k] + (float)b1[k]) * SCALE);
    }
    *(bf16x8*)&Tg[base] = o0;
    *(bf16x8*)&Tg[base + 8] = o1;
  } else {
    const int blk = blockIdx.x - 2048;
    const size_t ij0 = ((size_t)blk * 256 + tid) * 4;
    const float4 a = *(const float4*)&masks[ij0 * 3];
    const float4 b = *(const float4*)&masks[ij0 * 3 + 4];
    const float4 c = *(const float4*)&masks[ij0 * 3 + 8];
    const float m0[4] = {a.x, a.w, b.z, c.y};
    const float m1[4] = {a.y, b.x, b.w, c.z};
    const float m2[4] = {a.z, b.y, c.x, c.w};
#pragma unroll
    for (int h = 0; h < 16; ++h) {
      const float p0 = mproj[h], p1 = mproj[16 + h], p2 = mproj[32 + h];
      bf16x4 o;
#pragma unroll
      for (int k = 0; k < 4; ++k)
        o[k] = (__bf16)(m0[k] * p0 + m1[k] * p1 + m2[k] * p2);
      *(bf16x4*)&Mh[(size_t)h * 1048576 + ij0] = o;
    }
  }
}

// ---------------------------------------------------------------------------
// attn10: chunk=128, pipelined + setprio (r7 math, unchanged). INSTRUMENTATION
// SPLIT: launched twice with b0 in {0,2}, grid (32,16,2) each, so each
// dispatch is ~23-26 us and the heaviest non-attn kernel surfaces in the
// rocprof top-5. Revert to single dispatch after attribution.
// ---------------------------------------------------------------------------
__global__ __launch_bounds__(256, 6) void attn10(
    const __bf16* __restrict__ Tg, const __bf16* __restrict__ Mh,
    const __bf16* __restrict__ Vt, __bf16* __restrict__ av, const int b0)
{
  __shared__ __bf16 P[2][32 * 128];
  __shared__ float rinvS[32];
  const int tid = threadIdx.x;
  const int i0 = blockIdx.x * 32;
  const int h = blockIdx.y, b = blockIdx.z + b0;
  const int g = h >> 3;
  const size_t bg = (size_t)(b * 2 + g);
  const int r = tid >> 3, li = tid & 7;
  const __bf16* Trow = Tg + bg * 1048576 + (size_t)(i0 + r) * 1024 + li * 8;
  const __bf16* Mrow = Mh + (size_t)h * 1048576 + (size_t)(i0 + r) * 1024 + li * 8;

  const int lane = tid & 63, wv = tid >> 6;
  const int m = lane & 15, kq = lane >> 4;
  const __bf16* vbase = Vt + ((size_t)((b * 16 + h) * 64 + wv * 16 + m)) * 1024 + kq * 8;

  float sum = 0.f;
  f32x4 acc[2][2];
#pragma unroll
  for (int mt = 0; mt < 2; ++mt)
#pragma unroll
    for (int u = 0; u < 2; ++u)
      acc[mt][u] = (f32x4){0.f, 0.f, 0.f, 0.f};

  bf16x8 t[2], mk[2], v[4];
#pragma unroll
  for (int q = 0; q < 2; ++q) {
    t[q]  = *(const bf16x8*)&Trow[q * 64];
    mk[q] = *(const bf16x8*)&Mrow[q * 64];
  }

  for (int ch = 0; ch < 8; ++ch) {
    const int cb = ch & 1;
#pragma unroll
    for (int ks = 0; ks < 4; ++ks)
      v[ks] = *(const bf16x8*)&vbase[(ch * 4 + ks) * 32];
#pragma unroll
    for (int q = 0; q < 2; ++q) {
      bf16x8 p8;
      float s0 = 0.f;
#pragma unroll
      for (int k = 0; k < 8; ++k) {
        const float e = __expf((float)t[q][k] * (float)mk[q][k]);
        s0 += e;
        p8[k] = (__bf16)e;
      }
      sum += s0;
      const int slot = (q * 8 + li) ^ (r & 7);
      *(bf16x8*)&P[cb][r * 128 + slot * 8] = p8;
    }
    if (ch < 7) {
#pragma unroll
      for (int q = 0; q < 2; ++q) {
        t[q]  = *(const bf16x8*)&Trow[(ch + 1) * 128 + q * 64];
        mk[q] = *(const bf16x8*)&Mrow[(ch + 1) * 128 + q * 64];
      }
    }
    bar_lds();
    __builtin_amdgcn_s_setprio(1);
#pragma unroll
    for (int ks = 0; ks < 4; ++ks) {
      const int c = ks * 4 + kq;
#pragma unroll
      for (int mt = 0; mt < 2; ++mt) {
        const int R = mt * 16 + m;
        const bf16x8 a = *(const bf16x8*)&P[cb][R * 128 + ((c ^ (R & 7)) << 3)];
        acc[mt][ks & 1] = __builtin_amdgcn_mfma_f32_16x16x32_bf16(
            a, v[ks], acc[mt][ks & 1], 0, 0, 0);
      }
    }
    __builtin_amdgcn_s_setprio(0);
  }

  sum += __shfl_xor(sum, 1);
  sum += __shfl_xor(sum, 2);
  sum += __shfl_xor(sum, 4);
  if (li == 0) rinvS[r] = 1.f / sum;
  __syncthreads();

#pragma unroll
  for (int mt = 0; mt < 2; ++mt) {
    const f32x4 accf = acc[mt][0] + acc[mt][1];
#pragma unroll
    for (int reg = 0; reg < 4; ++reg) {
      const int row = mt * 16 + kq * 4 + reg;
      av[((size_t)(i0 + row) * 4 + b) * 1024 + h * 64 + wv * 16 + m] =
          (__bf16)(accf[reg] * rinvS[row]);
    }
  }
}

// ---------------------------------------------------------------------------
// residual + LayerNorm: float4 loads, wave-shuffle reduce (2 barriers).
// Sums the two K-split partials of the Wo projection.
// ---------------------------------------------------------------------------
__global__ __launch_bounds__(256) void ln_kernel(
    const float* __restrict__ w, const float* __restrict__ ao0,
    const float* __restrict__ ao1,
    const float* __restrict__ gamma, const float* __restrict__ beta,
    float* __restrict__ out)
{
  const int tid = threadIdx.x;
  const int lane = tid & 63, wv = tid >> 6;
  const size_t base = (size_t)blockIdx.x * DMODEL + tid * 4;
  __shared__ float red[8];
  const float4 xw = *(const float4*)&w[base];
  const float4 xa = *(const float4*)&ao0[base];
  const float4 xb = *(const float4*)&ao1[base];
  float x[4] = {xw.x + xa.x + xb.x, xw.y + xa.y + xb.y,
                xw.z + xa.z + xb.z, xw.w + xa.w + xb.w};
  float s = (x[0] + x[1]) + (x[2] + x[3]);
  s += __shfl_xor(s, 1);  s += __shfl_xor(s, 2);  s += __shfl_xor(s, 4);
  s += __shfl_xor(s, 8);  s += __shfl_xor(s, 16); s += __shfl_xor(s, 32);
  if (lane == 0) red[wv] = s;
  __syncthreads();
  const float mu = (red[0] + red[1] + red[2] + red[3]) * (1.f / DMODEL);
  float s2 = 0.f;
#pragma unroll
  for (int p = 0; p < 4; ++p) { const float t = x[p] - mu; s2 += t * t; }
  s2 += __shfl_xor(s2, 1);  s2 += __shfl_xor(s2, 2);  s2 += __shfl_xor(s2, 4);
  s2 += __shfl_xor(s2, 8);  s2 += __shfl_xor(s2, 16); s2 += __shfl_xor(s2, 32);
  if (lane == 0) red[4 + wv] = s2;
  __syncthreads();
  const float rs = rsqrtf((red[4] + red[5] + red[6] + red[7]) * (1.f / DMODEL) + LN_EPS);
  const float4 g4 = *(const float4*)&gamma[tid * 4];
  const float4 b4 = *(const float4*)&beta[tid * 4];
  float4 o;
  o.x = (x[0] - mu) * rs * g4.x + b4.x;
  o.y = (x[1] - mu) * rs * g4.y + b4.y;
  o.z = (x[2] - mu) * rs * g4.z + b4.z;
  o.w = (x[3] - mu) * rs * g4.w + b4.w;
  *(float4*)&out[base] = o;
}

// ---------------------------------------------------------------------------
extern "C" void kernel_launch(void* const* d_in, const int* in_sizes, int n_in,
                              void* d_out, int out_size, void* d_ws, size_t ws_size,
                              hipStream_t stream)
{
  const float* w     = (const float*)d_in[0];
  const float* r     = (const float*)d_in[1];
  const float* rwb   = (const float*)d_in[2];
  const float* rrb   = (const float*)d_in[3];
  const float* masks = (const float*)d_in[4];
  const float* Wqkv  = (const float*)d_in[5];
  const float* Wr    = (const float*)d_in[6];
  const float* mproj = (const float*)d_in[7];
  const float* Wo    = (const float*)d_in[8];
  const float* gam   = (const float*)d_in[9];
  const float* bet   = (const float*)d_in[10];
  float* out = (float*)d_out;

  float* ws = (float*)d_ws;
  // fp32-unit offsets; total 25,690,112 f = 102.8 MB
  __bf16* w_bf    = (__bf16*)(ws);                   // 2,097,152 f
  __bf16* Wqkv_bf = (__bf16*)(ws + 2097152);         //   655,360 f
  __bf16* r_bf    = (__bf16*)(ws + 2752512);         //   524,288 f
  __bf16* Wr_bf   = (__bf16*)(ws + 3276800);         //    65,536 f
  __bf16* Qw      = (__bf16*)(ws + 3342336);         //   262,144 f
  __bf16* Qr      = (__bf16*)(ws + 3604480);
  __bf16* Kb      = (__bf16*)(ws + 3866624);
  __bf16* Rb      = (__bf16*)(ws + 4128768);         //    65,536 f
  __bf16* Mh      = (__bf16*)(ws);                   // 8,388,608 f (post-gemm_proj)
  __bf16* AC_bf   = (__bf16*)(ws + 8388608);         // 4,194,304 f
  float*  ao0     = ws + 8388608;                    // overlays AC (post-prep3)
  __bf16* BD_bf   = (__bf16*)(ws + 12582912);        // 4,194,304 f (SHIFTED)
  float*  ao1     = ws + 12582912;                   // overlays BD (post-prep3)
  __bf16* Tg      = (__bf16*)(ws + 16777216);        // 4,194,304 f
  __bf16* Vt      = (__bf16*)(ws + 20971520);        // 2,097,152 f
  __bf16* av_bf   = (__bf16*)(ws + 23068672);        // 2,097,152 f
  __bf16* Wo_bf   = (__bf16*)(ws + 25165824);        //   524,288 f

  // 1) all input casts
  cast_all<<<3776, 256, 0, stream>>>(w, w_bf, Wqkv, Wqkv_bf, r, r_bf,
                                     Wr, Wr_bf, Wo, Wo_bf);
  // 2) merged QKV + r projections (BK=64)
  gemm_proj<<<656, 256, 0, stream>>>(
      w_bf, Wqkv_bf, r_bf, Wr_bf, rwb, rrb, Qw, Qr, Kb, Vt, Rb);
  // 3) AC + shifted-BD via MFMA
  gemm64_bf16<<<dim3(8, 8, 16), 256, 0, stream>>>(Qw, Qr, Kb, Rb, AC_bf, BD_bf);
  // 4) T = (AC+BDs)*SCALE (vectorized) + per-head masks, one dispatch
  prep3<<<3072, 256, 0, stream>>>(AC_bf, BD_bf, Tg, masks, mproj, Mh);
  // 5) attention, SPLIT IN TWO for rocprof attribution (b in {0,1} / {2,3})
  attn10<<<dim3(32, 16, 2), 256, 0, stream>>>(Tg, Mh, Vt, av_bf, 0);
  attn10<<<dim3(32, 16, 2), 256, 0, stream>>>(Tg, Mh, Vt, av_bf, 2);
  // 6) output projection, BK=64 K-split x2 -> fp32 partials
  gemm_wo<<<dim3(16, 32, 2), 256, 0, stream>>>(av_bf, Wo_bf, ao0, ao1);
  // 7) residual + LayerNorm (sums the two partials)
  ln_kernel<<<4096, 256, 0, stream>>>(w, ao0, ao1, gam, bet, out);
}